// Round 7
// baseline (648.440 us; speedup 1.0000x reference)
//
#include <hip/hip_runtime.h>
#include <hip/hip_bf16.h>

#define NN 6144
#define NF 512
#define NH 256
#define JSPLIT 4
#define JSLICE (NN / JSPLIT)   // 1536
#define BR 32                  // K3 rows per block
#define NT (JSLICE / 64)       // 24 j-tiles per block
#define NW (NN / 64)           // 96 mask words per row

typedef __attribute__((ext_vector_type(4))) float f32x4;
typedef __attribute__((ext_vector_type(8))) short s16x8;
typedef __attribute__((ext_vector_type(4))) short s16x4;

__device__ __forceinline__ ushort f2bf(float f) {
    unsigned u = __builtin_bit_cast(unsigned, f);
    u += 0x7fffu + ((u >> 16) & 1u);   // RNE (finite values only)
    return (ushort)(u >> 16);
}

__device__ __forceinline__ float bf2f(ushort u) {
    unsigned v = ((unsigned)u) << 16;
    return __builtin_bit_cast(float, v);
}

__device__ __forceinline__ float wave_red_add(float v) {
#pragma unroll
    for (int s = 32; s; s >>= 1) v += __shfl_xor(v, s);
    return v;
}

// ---------------- K0: W (512x256 f32, k-major) -> WbT (256x512 bf16, n-major)
__global__ __launch_bounds__(256) void k0_prep(const float* __restrict__ W,
                                               ushort* __restrict__ WbT) {
    int idx = blockIdx.x * 256 + threadIdx.x;   // 0..131071
    int k = idx >> 8, n = idx & 255;
    WbT[n * NF + k] = f2bf(W[idx]);
}

// ---------------- K1m: fused {Wh = x @ W  GEMM} + {adj -> u64 bitmask}
// blocks 0..191: GEMM (rb = bid%48, cb = bid/48)
// blocks 192..1727: mask rows (bid-192)*4 + wid, ballot over 64-j groups
__global__ __launch_bounds__(256) void k1m(const float* __restrict__ x,
                                           const ushort* __restrict__ WbT,
                                           const int* __restrict__ adj,
                                           float* __restrict__ Wh,
                                           ushort* __restrict__ B2,
                                           unsigned long long* __restrict__ maskb) {
    const int bid = blockIdx.x;
    const int t = threadIdx.x, lane = t & 63, wid = t >> 6;

    if (bid >= 192) {
        // ---- mask generation: one wave per row
        const int row = (bid - 192) * 4 + wid;
        const int* ap = adj + (size_t)row * NN + lane;
        unsigned long long* mrow = maskb + (size_t)row * NW;
#pragma unroll 4
        for (int jt = 0; jt < NW; ++jt) {
            int v = ap[jt * 64];
            unsigned long long b = __ballot(v != 0);
            if (lane == 0) mrow[jt] = b;
        }
        return;
    }

    // ---- GEMM part
    __shared__ ushort Asm[128 * 64];   // [row][k] swizzled
    __shared__ ushort Bsm[64 * 64];    // [n][k] swizzled
    const int rb = bid % 48;   // 128 rows
    const int cb = bid / 48;   // 64 cols
    const int wrow = wid >> 1, wcol = wid & 1;
    f32x4 acc[4][2];
#pragma unroll
    for (int i = 0; i < 4; ++i)
#pragma unroll
        for (int j = 0; j < 2; ++j) acc[i][j] = (f32x4){0.f, 0.f, 0.f, 0.f};

    for (int kt = 0; kt < NF; kt += 64) {
        __syncthreads();
#pragma unroll
        for (int c = 0; c < 4; ++c) {
            int idx = c * 256 + t;           // 0..1023
            int row = idx >> 3, k8 = idx & 7;
            const float* src = x + (rb * 128 + row) * NF + kt + k8 * 8;
            float4 lo = *reinterpret_cast<const float4*>(src);
            float4 hi = *reinterpret_cast<const float4*>(src + 4);
            union { s16x8 v; ushort u[8]; } pk;
            pk.u[0] = f2bf(lo.x); pk.u[1] = f2bf(lo.y);
            pk.u[2] = f2bf(lo.z); pk.u[3] = f2bf(lo.w);
            pk.u[4] = f2bf(hi.x); pk.u[5] = f2bf(hi.y);
            pk.u[6] = f2bf(hi.z); pk.u[7] = f2bf(hi.w);
            int byte = (row * 128 + k8 * 16) ^ ((row & 7) << 4);
            *reinterpret_cast<s16x8*>((char*)Asm + byte) = pk.v;
        }
#pragma unroll
        for (int c = 0; c < 2; ++c) {
            int idx = c * 256 + t;           // 0..511
            int row = idx >> 3, k8 = idx & 7;
            s16x8 v = *reinterpret_cast<const s16x8*>(WbT + (cb * 64 + row) * NF + kt + k8 * 8);
            int byte = (row * 128 + k8 * 16) ^ ((row & 7) << 4);
            *reinterpret_cast<s16x8*>((char*)Bsm + byte) = v;
        }
        __syncthreads();
#pragma unroll
        for (int kk = 0; kk < 64; kk += 32) {
            const int kbyte = (kk + ((lane >> 4) * 8)) * 2;
            s16x8 af[4], bfr[2];
#pragma unroll
            for (int fi = 0; fi < 4; ++fi) {
                int row = wrow * 64 + fi * 16 + (lane & 15);
                int byte = (row * 128 + kbyte) ^ ((row & 7) << 4);
                af[fi] = *reinterpret_cast<const s16x8*>((char*)Asm + byte);
            }
#pragma unroll
            for (int fj = 0; fj < 2; ++fj) {
                int nn = wcol * 32 + fj * 16 + (lane & 15);
                int byte = (nn * 128 + kbyte) ^ ((nn & 7) << 4);
                bfr[fj] = *reinterpret_cast<const s16x8*>((char*)Bsm + byte);
            }
#pragma unroll
            for (int fi = 0; fi < 4; ++fi)
#pragma unroll
                for (int fj = 0; fj < 2; ++fj)
                    acc[fi][fj] = __builtin_amdgcn_mfma_f32_16x16x32_bf16(
                        af[fi], bfr[fj], acc[fi][fj], 0, 0, 0);
        }
    }
#pragma unroll
    for (int fi = 0; fi < 4; ++fi)
#pragma unroll
        for (int fj = 0; fj < 2; ++fj) {
            int grow0 = rb * 128 + wrow * 64 + fi * 16 + (lane >> 4) * 4;  // j; %8 in {0,4}
            int gcol = cb * 64 + wcol * 32 + fj * 16 + (lane & 15);
            union { s16x4 v; ushort u[4]; } pk;
#pragma unroll
            for (int r = 0; r < 4; ++r) {
                float v = acc[fi][fj][r];
                Wh[(grow0 + r) * NH + gcol] = v;
                pk.u[r] = f2bf(v);
            }
            *reinterpret_cast<s16x4*>(B2 + (grow0 >> 3) * 2048 + gcol * 8 + (grow0 & 7)) = pk.v;
        }
}

// ---------------- K2: f1 = Wh@a1, f2 = Wh@a2 (one wave per row)
__global__ __launch_bounds__(256) void k2_f12(const float* __restrict__ Wh,
                                              const float* __restrict__ a,
                                              float* __restrict__ f1,
                                              float* __restrict__ f2) {
    int row = blockIdx.x * 4 + (threadIdx.x >> 6);
    int lane = threadIdx.x & 63;
    float4 wv = *reinterpret_cast<const float4*>(Wh + row * NH + lane * 4);
    float4 a1 = *reinterpret_cast<const float4*>(a + lane * 4);
    float4 a2 = *reinterpret_cast<const float4*>(a + NH + lane * 4);
    float d1 = wv.x * a1.x + wv.y * a1.y + wv.z * a1.z + wv.w * a1.w;
    float d2 = wv.x * a2.x + wv.y * a2.y + wv.z * a2.z + wv.w * a2.w;
    d1 = wave_red_add(d1);
    d2 = wave_red_add(d2);
    if (lane == 0) { f1[row] = d1; f2[row] = d2; }
}

// ---------------- K3: barrier-free, LDS-free fused attention, mask-driven
// Block: 4 independent waves; wave owns 32 rows x 64 cols. w-values built
// directly as MFMA A-fragments in registers from u64 row-masks (L2-resident,
// broadcast loads) + f1/f2. B2 blocked layout -> 4x256B dense segments/instr.
// No barriers; 12 waves/CU of free-running TLP.
__global__ __launch_bounds__(256, 3) void k3_attn(const unsigned long long* __restrict__ maskb,
                                                  const ushort* __restrict__ B2,
                                                  const float* __restrict__ f1,
                                                  const float* __restrict__ f2,
                                                  ushort* __restrict__ hpart,
                                                  float* __restrict__ Zpart) {
    const int t = threadIdx.x, lane = t & 63, wid = t >> 6;
    const int rb = blockIdx.x;        // 0..191 (32 rows each)
    const int js = blockIdx.y;        // 0..JSPLIT-1
    const int row0 = rb * BR;
    const int j0 = js * JSLICE;
    const int r15 = lane & 15, l4 = lane >> 4;
    const int sh = l4 * 8;            // this lane's j-subchunk bit offset

    const float f1v0 = f1[row0 + r15];
    const float f1v1 = f1[row0 + 16 + r15];
    const unsigned long long* mp0 = maskb + (size_t)(row0 + r15) * NW + (j0 >> 6);
    const unsigned long long* mp1 = mp0 + 16 * NW;
    const float* f2p = f2 + j0 + sh;
    const ushort* bb = B2 + ((size_t)(j0 >> 3) + l4) * 2048 + (wid * 64 + r15) * 8;

    f32x4 acc[2][4];
#pragma unroll
    for (int i = 0; i < 2; ++i)
#pragma unroll
        for (int j = 0; j < 4; ++j) acc[i][j] = (f32x4){0.f, 0.f, 0.f, 0.f};
    float zs0 = 0.f, zs1 = 0.f;

    unsigned long long m0[2], m1[2];
    m0[0] = mp0[0];
    m1[0] = mp1[0];

#pragma unroll
    for (int jt = 0; jt < NT; ++jt) {
        const int cur = jt & 1, nxt = cur ^ 1;   // compile-time (full unroll)
        // prefetch next tile's masks (L2-resident, hides under wgen+MFMA)
        if (jt + 1 < NT) { m0[nxt] = mp0[jt + 1]; m1[nxt] = mp1[jt + 1]; }
        // f2 values for this lane's j-subchunks (L1-resident broadcasts)
        f32x4 g[2][2];
#pragma unroll
        for (int kk = 0; kk < 2; ++kk)
#pragma unroll
            for (int h = 0; h < 2; ++h)
                g[kk][h] = *reinterpret_cast<const f32x4*>(f2p + jt * 64 + kk * 32 + h * 4);
        // --- wgen: build A-fragments in registers from mask bits
        s16x8 af[2][2];
#pragma unroll
        for (int fi = 0; fi < 2; ++fi) {
            const unsigned long long m = fi ? m1[cur] : m0[cur];
            const float f1v = fi ? f1v1 : f1v0;
#pragma unroll
            for (int kk = 0; kk < 2; ++kk) {
                const unsigned mb = (unsigned)(m >> (kk * 32 + sh)) & 0xFFu;
                union { s16x8 v; ushort u[8]; } pk;
                float zl = 0.f;
#pragma unroll
                for (int q = 0; q < 8; ++q) {
                    float e = f1v + g[kk][q >> 2][q & 3];
                    e = e > 0.f ? e : 0.2f * e;
                    float w = ((mb >> q) & 1u) ? __expf(e) : 0.f;
                    zl += w;
                    pk.u[q] = f2bf(w);
                }
                if (fi) zs1 += zl; else zs0 += zl;
                af[fi][kk] = pk.v;
            }
        }
        // --- B loads + MFMA (B2 is L2-resident; 4x256B dense per instr)
#pragma unroll
        for (int kk = 0; kk < 2; ++kk) {
            const ushort* bt = bb + (size_t)(jt * 8 + kk * 4) * 2048;
#pragma unroll
            for (int fj = 0; fj < 4; ++fj) {
                s16x8 bv = *reinterpret_cast<const s16x8*>(bt + fj * 128);
                acc[0][fj] = __builtin_amdgcn_mfma_f32_16x16x32_bf16(
                    af[0][kk], bv, acc[0][fj], 0, 0, 0);
                acc[1][fj] = __builtin_amdgcn_mfma_f32_16x16x32_bf16(
                    af[1][kk], bv, acc[1][fj], 0, 0, 0);
            }
        }
    }

    // --- epilogue: hpart bf16, layout [(row*JSPLIT + js)*256 + col]
#pragma unroll
    for (int fi = 0; fi < 2; ++fi)
#pragma unroll
        for (int fj = 0; fj < 4; ++fj) {
            int prow0 = row0 + fi * 16 + l4 * 4;
            int pcol = wid * 64 + fj * 16 + r15;
#pragma unroll
            for (int r = 0; r < 4; ++r)
                hpart[(size_t)(prow0 + r) * (JSPLIT * NH) + js * NH + pcol] =
                    f2bf(acc[fi][fj][r]);
        }
    // --- Z: all 4 waves computed identical sums; wave 0 writes
    zs0 += __shfl_xor(zs0, 16); zs0 += __shfl_xor(zs0, 32);
    zs1 += __shfl_xor(zs1, 16); zs1 += __shfl_xor(zs1, 32);
    if (wid == 0 && lane < 16) {
        Zpart[js * NN + row0 + lane] = zs0;
        Zpart[js * NN + row0 + 16 + lane] = zs1;
    }
}

// ---------------- K4: combine j-split partials (bf16), normalize, elu, two dots
__global__ __launch_bounds__(256) void k4_reduce(const ushort* __restrict__ hpart,
                                                 const float* __restrict__ Zpart,
                                                 const float* __restrict__ fcW,
                                                 float* __restrict__ out1,
                                                 float* __restrict__ p) {
    int row = blockIdx.x * 4 + (threadIdx.x >> 6);
    int lane = threadIdx.x & 63;
    float s[4] = {0.f, 0.f, 0.f, 0.f};
    float Z = 0.f;
#pragma unroll
    for (int js = 0; js < JSPLIT; ++js) {
        union { s16x4 v; ushort u[4]; } hv;
        hv.v = *reinterpret_cast<const s16x4*>(hpart + (size_t)row * (JSPLIT * NH) + js * NH + lane * 4);
#pragma unroll
        for (int r = 0; r < 4; ++r) s[r] += bf2f(hv.u[r]);
        Z += Zpart[js * NN + row];
    }
    float inv = 1.f / Z;
    float h[4];
#pragma unroll
    for (int r = 0; r < 4; ++r) {
        float v = s[r] * inv;
        h[r] = v > 0.f ? v : expm1f(v);   // elu, alpha=1
    }
    float4 fc1 = *reinterpret_cast<const float4*>(fcW + lane * 4);
    float4 fc2 = *reinterpret_cast<const float4*>(fcW + NH + lane * 4);
    float d1 = h[0] * fc1.x + h[1] * fc1.y + h[2] * fc1.z + h[3] * fc1.w;
    float d2 = h[0] * fc2.x + h[1] * fc2.y + h[2] * fc2.z + h[3] * fc2.w;
    d1 = wave_red_add(d1);
    d2 = wave_red_add(d2);
    if (lane == 0) { out1[row] = d1; p[row] = d2; }
}

// ---------------- K5: c = sum(p) + fcb; out = out1 + c (single block, deterministic)
__global__ __launch_bounds__(256) void k5_final(const float* __restrict__ out1,
                                                const float* __restrict__ p,
                                                const float* __restrict__ fcb,
                                                float* __restrict__ out) {
    __shared__ float red[256];
    int t = threadIdx.x;
    float s = 0.f;
    for (int i = t; i < NN; i += 256) s += p[i];
    red[t] = s;
    __syncthreads();
    for (int h = 128; h; h >>= 1) {
        if (t < h) red[t] += red[t + h];
        __syncthreads();
    }
    float c = red[0] + fcb[0];
    for (int i = t; i < NN; i += 256) out[i] = out1[i] + c;
}

extern "C" void kernel_launch(void* const* d_in, const int* in_sizes, int n_in,
                              void* d_out, int out_size, void* d_ws, size_t ws_size,
                              hipStream_t stream) {
    const float* x   = (const float*)d_in[0];
    const int*   adj = (const int*)d_in[1];
    const float* W   = (const float*)d_in[2];
    const float* a   = (const float*)d_in[3];
    const float* fcW = (const float*)d_in[4];
    const float* fcb = (const float*)d_in[5];
    float* out = (float*)d_out;
    char* ws = (char*)d_ws;

    // sizes verified: total 27,197,440 bytes (< 35.2 MB proven in R5)
    constexpr size_t oWbT   = 0;                           // 256*512*2       = 262144
    constexpr size_t oB2    = oWbT + 262144;               // 768*256*8*2     = 3145728
    constexpr size_t oWh    = oB2 + 3145728;               // 6144*256*4      = 6291456
    constexpr size_t oF1    = oWh + 6291456;               // 24576
    constexpr size_t oF2    = oF1 + 24576;                 // 24576
    constexpr size_t oMask  = oF2 + 24576;                 // 6144*96*8       = 4718592
    constexpr size_t oHp    = oMask + 4718592;             // 6144*4*256*2    = 12582912
    constexpr size_t oZp    = oHp + 12582912;              // 4*6144*4        = 98304
    constexpr size_t oOut1  = oZp + 98304;                 // 24576
    constexpr size_t oP     = oOut1 + 24576;               // 24576

    ushort* WbT  = (ushort*)(ws + oWbT);
    ushort* B2   = (ushort*)(ws + oB2);
    float*  Wh   = (float*)(ws + oWh);
    float*  f1   = (float*)(ws + oF1);
    float*  f2   = (float*)(ws + oF2);
    unsigned long long* mk = (unsigned long long*)(ws + oMask);
    ushort* hp   = (ushort*)(ws + oHp);
    float*  Zp   = (float*)(ws + oZp);
    float*  out1 = (float*)(ws + oOut1);
    float*  p    = (float*)(ws + oP);

    k0_prep<<<dim3(512), dim3(256), 0, stream>>>(W, WbT);
    k1m<<<dim3(192 + NN / 4), dim3(256), 0, stream>>>(x, WbT, adj, Wh, B2, mk);
    k2_f12<<<dim3(1536), dim3(256), 0, stream>>>(Wh, a, f1, f2);
    k3_attn<<<dim3(NN / BR, JSPLIT), dim3(256), 0, stream>>>(mk, B2, f1, f2, hp, Zp);
    k4_reduce<<<dim3(1536), dim3(256), 0, stream>>>(hp, Zp, fcW, out1, p);
    k5_final<<<dim3(1), dim3(256), 0, stream>>>(out1, p, fcb, out);
}

// Round 8
// 159.206 us; speedup vs baseline: 4.0730x; 4.0730x over previous
//
#include <hip/hip_runtime.h>
#include <hip/hip_bf16.h>

#define NN 6144
#define NF 512
#define NH 256
#define BR 32                  // K3 rows per block
#define NTT (NN / 64)          // 96 j-tiles total
#define NW (NN / 64)           // 96 mask words per row
#define HSTRIDE 132            // padded LDS row stride (f32)

typedef __attribute__((ext_vector_type(4))) float f32x4;
typedef __attribute__((ext_vector_type(2))) float f32x2;
typedef __attribute__((ext_vector_type(8))) short s16x8;
typedef __attribute__((ext_vector_type(4))) short s16x4;

__device__ __forceinline__ ushort f2bf(float f) {
    unsigned u = __builtin_bit_cast(unsigned, f);
    u += 0x7fffu + ((u >> 16) & 1u);   // RNE (finite values only)
    return (ushort)(u >> 16);
}

__device__ __forceinline__ float wave_red_add(float v) {
#pragma unroll
    for (int s = 32; s; s >>= 1) v += __shfl_xor(v, s);
    return v;
}

// ---------------- K0: W (512x256 f32, k-major) -> WbT (256x512 bf16, n-major)
__global__ __launch_bounds__(256) void k0_prep(const float* __restrict__ W,
                                               ushort* __restrict__ WbT) {
    int idx = blockIdx.x * 256 + threadIdx.x;   // 0..131071
    int k = idx >> 8, n = idx & 255;
    WbT[n * NF + k] = f2bf(W[idx]);
}

// ---------------- K1m: fused {Wh = x @ W  GEMM} + {adj -> u64 bitmask}
__global__ __launch_bounds__(256) void k1m(const float* __restrict__ x,
                                           const ushort* __restrict__ WbT,
                                           const int* __restrict__ adj,
                                           float* __restrict__ Wh,
                                           ushort* __restrict__ B2,
                                           unsigned long long* __restrict__ maskb) {
    const int bid = blockIdx.x;
    const int t = threadIdx.x, lane = t & 63, wid = t >> 6;

    if (bid >= 192) {
        // ---- mask generation: one wave per row (coalesced 256B adj reads)
        const int row = (bid - 192) * 4 + wid;
        const int* ap = adj + (size_t)row * NN + lane;
        unsigned long long* mrow = maskb + (size_t)row * NW;
#pragma unroll 4
        for (int jt = 0; jt < NW; ++jt) {
            int v = ap[jt * 64];
            unsigned long long b = __ballot(v != 0);
            if (lane == 0) mrow[jt] = b;
        }
        return;
    }

    // ---- GEMM part
    __shared__ ushort Asm[128 * 64];   // [row][k] swizzled
    __shared__ ushort Bsm[64 * 64];    // [n][k] swizzled
    const int rb = bid % 48;   // 128 rows
    const int cb = bid / 48;   // 64 cols
    const int wrow = wid >> 1, wcol = wid & 1;
    f32x4 acc[4][2];
#pragma unroll
    for (int i = 0; i < 4; ++i)
#pragma unroll
        for (int j = 0; j < 2; ++j) acc[i][j] = (f32x4){0.f, 0.f, 0.f, 0.f};

    for (int kt = 0; kt < NF; kt += 64) {
        __syncthreads();
#pragma unroll
        for (int c = 0; c < 4; ++c) {
            int idx = c * 256 + t;           // 0..1023
            int row = idx >> 3, k8 = idx & 7;
            const float* src = x + (rb * 128 + row) * NF + kt + k8 * 8;
            float4 lo = *reinterpret_cast<const float4*>(src);
            float4 hi = *reinterpret_cast<const float4*>(src + 4);
            union { s16x8 v; ushort u[8]; } pk;
            pk.u[0] = f2bf(lo.x); pk.u[1] = f2bf(lo.y);
            pk.u[2] = f2bf(lo.z); pk.u[3] = f2bf(lo.w);
            pk.u[4] = f2bf(hi.x); pk.u[5] = f2bf(hi.y);
            pk.u[6] = f2bf(hi.z); pk.u[7] = f2bf(hi.w);
            int byte = (row * 128 + k8 * 16) ^ ((row & 7) << 4);
            *reinterpret_cast<s16x8*>((char*)Asm + byte) = pk.v;
        }
#pragma unroll
        for (int c = 0; c < 2; ++c) {
            int idx = c * 256 + t;           // 0..511
            int row = idx >> 3, k8 = idx & 7;
            s16x8 v = *reinterpret_cast<const s16x8*>(WbT + (cb * 64 + row) * NF + kt + k8 * 8);
            int byte = (row * 128 + k8 * 16) ^ ((row & 7) << 4);
            *reinterpret_cast<s16x8*>((char*)Bsm + byte) = v;
        }
        __syncthreads();
#pragma unroll
        for (int kk = 0; kk < 64; kk += 32) {
            const int kbyte = (kk + ((lane >> 4) * 8)) * 2;
            s16x8 af[4], bfr[2];
#pragma unroll
            for (int fi = 0; fi < 4; ++fi) {
                int row = wrow * 64 + fi * 16 + (lane & 15);
                int byte = (row * 128 + kbyte) ^ ((row & 7) << 4);
                af[fi] = *reinterpret_cast<const s16x8*>((char*)Asm + byte);
            }
#pragma unroll
            for (int fj = 0; fj < 2; ++fj) {
                int nn = wcol * 32 + fj * 16 + (lane & 15);
                int byte = (nn * 128 + kbyte) ^ ((nn & 7) << 4);
                bfr[fj] = *reinterpret_cast<const s16x8*>((char*)Bsm + byte);
            }
#pragma unroll
            for (int fi = 0; fi < 4; ++fi)
#pragma unroll
                for (int fj = 0; fj < 2; ++fj)
                    acc[fi][fj] = __builtin_amdgcn_mfma_f32_16x16x32_bf16(
                        af[fi], bfr[fj], acc[fi][fj], 0, 0, 0);
        }
    }
#pragma unroll
    for (int fi = 0; fi < 4; ++fi)
#pragma unroll
        for (int fj = 0; fj < 2; ++fj) {
            int grow0 = rb * 128 + wrow * 64 + fi * 16 + (lane >> 4) * 4;  // j; %8 in {0,4}
            int gcol = cb * 64 + wcol * 32 + fj * 16 + (lane & 15);
            union { s16x4 v; ushort u[4]; } pk;
#pragma unroll
            for (int r = 0; r < 4; ++r) {
                float v = acc[fi][fj][r];
                Wh[(grow0 + r) * NH + gcol] = v;
                pk.u[r] = f2bf(v);
            }
            *reinterpret_cast<s16x4*>(B2 + (grow0 >> 3) * 2048 + gcol * 8 + (grow0 & 7)) = pk.v;
        }
}

// ---------------- K2: f1 = Wh@a1, f2 = Wh@a2 (one wave per row)
__global__ __launch_bounds__(256) void k2_f12(const float* __restrict__ Wh,
                                              const float* __restrict__ a,
                                              float* __restrict__ f1,
                                              float* __restrict__ f2) {
    int row = blockIdx.x * 4 + (threadIdx.x >> 6);
    int lane = threadIdx.x & 63;
    float4 wv = *reinterpret_cast<const float4*>(Wh + row * NH + lane * 4);
    float4 a1 = *reinterpret_cast<const float4*>(a + lane * 4);
    float4 a2 = *reinterpret_cast<const float4*>(a + NH + lane * 4);
    float d1 = wv.x * a1.x + wv.y * a1.y + wv.z * a1.z + wv.w * a1.w;
    float d2 = wv.x * a2.x + wv.y * a2.y + wv.z * a2.z + wv.w * a2.w;
    d1 = wave_red_add(d1);
    d2 = wave_red_add(d2);
    if (lane == 0) { f1[row] = d1; f2[row] = d2; }
}

// ---------------- K3: fully-fused attention — FINAL rows, no partial outputs
// Block: 32 rows x 128 cols (grid 192 x 2 = 384). 4 waves; wave wid sweeps
// j-tiles jt = wid, wid+4, ... (all 96 tiles covered once per block).
// Barrier-free main loop; mask-driven wgen -> A-frags in registers; B2 dense
// segment loads. End: 2-phase LDS combine (34KB) + in-block finalize
// (1/Z, elu, fcW dots) -> writes only 2 floats per row.
__global__ __launch_bounds__(256) void k3_attn(const unsigned long long* __restrict__ maskb,
                                               const ushort* __restrict__ B2,
                                               const float* __restrict__ f1,
                                               const float* __restrict__ f2,
                                               const float* __restrict__ fcW,
                                               float* __restrict__ out1h,
                                               float* __restrict__ ph) {
    __shared__ float Hlds[2][BR * HSTRIDE];   // 2 x 16.9 KB
    __shared__ float Zlds[2][BR];
    const int t = threadIdx.x, lane = t & 63, wid = t >> 6;
    const int rb = blockIdx.x;        // 0..191 (32 rows each)
    const int cb = blockIdx.y;        // 0..1   (128 cols each)
    const int row0 = rb * BR;
    const int col0 = cb * 128;
    const int r15 = lane & 15, l4 = lane >> 4;
    const int sh = l4 * 8;            // this lane's j-subchunk bit offset

    const float f1v0 = f1[row0 + r15];
    const float f1v1 = f1[row0 + 16 + r15];
    const unsigned long long* mp0 = maskb + (size_t)(row0 + r15) * NW;
    const unsigned long long* mp1 = mp0 + 16 * NW;
    const float* f2p = f2 + sh;
    const ushort* bb = B2 + (size_t)l4 * 2048 + (col0 + r15) * 8;

    f32x4 acc[2][8];
#pragma unroll
    for (int i = 0; i < 2; ++i)
#pragma unroll
        for (int j = 0; j < 8; ++j) acc[i][j] = (f32x4){0.f, 0.f, 0.f, 0.f};
    float zs0 = 0.f, zs1 = 0.f;

#pragma unroll 2
    for (int it = 0; it < NTT / 4; ++it) {
        const int jt = wid + it * 4;
        // masks + f2 for this tile (L2/L1-resident)
        const unsigned long long m0 = mp0[jt];
        const unsigned long long m1 = mp1[jt];
        f32x4 g[2][2];
#pragma unroll
        for (int kk = 0; kk < 2; ++kk)
#pragma unroll
            for (int h = 0; h < 2; ++h)
                g[kk][h] = *reinterpret_cast<const f32x4*>(f2p + jt * 64 + kk * 32 + h * 4);
        // --- wgen: build A-fragments in registers from mask bits
        s16x8 af[2][2];
#pragma unroll
        for (int fi = 0; fi < 2; ++fi) {
            const unsigned long long m = fi ? m1 : m0;
            const float f1v = fi ? f1v1 : f1v0;
#pragma unroll
            for (int kk = 0; kk < 2; ++kk) {
                const unsigned mb = (unsigned)(m >> (kk * 32 + sh)) & 0xFFu;
                union { s16x8 v; ushort u[8]; } pk;
                float zl = 0.f;
#pragma unroll
                for (int q = 0; q < 8; ++q) {
                    float e = f1v + g[kk][q >> 2][q & 3];
                    e = e > 0.f ? e : 0.2f * e;
                    float w = ((mb >> q) & 1u) ? __expf(e) : 0.f;
                    zl += w;
                    pk.u[q] = f2bf(w);
                }
                if (fi) zs1 += zl; else zs0 += zl;
                af[fi][kk] = pk.v;
            }
        }
        // --- B loads + MFMA (B2 L2-resident; 4x256B dense per instr)
#pragma unroll
        for (int kk = 0; kk < 2; ++kk) {
            const ushort* bt = bb + (size_t)(jt * 8 + kk * 4) * 2048;
#pragma unroll
            for (int fj = 0; fj < 8; ++fj) {
                s16x8 bv = *reinterpret_cast<const s16x8*>(bt + fj * 128);
                acc[0][fj] = __builtin_amdgcn_mfma_f32_16x16x32_bf16(
                    af[0][kk], bv, acc[0][fj], 0, 0, 0);
                acc[1][fj] = __builtin_amdgcn_mfma_f32_16x16x32_bf16(
                    af[1][kk], bv, acc[1][fj], 0, 0, 0);
            }
        }
    }

    // --- combine phase 1: waves 0,1 write their partials; Z row-sums ready
    zs0 += __shfl_xor(zs0, 16); zs0 += __shfl_xor(zs0, 32);
    zs1 += __shfl_xor(zs1, 16); zs1 += __shfl_xor(zs1, 32);
    if (wid < 2) {
        float* myH = &Hlds[wid][0];
#pragma unroll
        for (int fi = 0; fi < 2; ++fi)
#pragma unroll
            for (int fj = 0; fj < 8; ++fj)
#pragma unroll
                for (int r = 0; r < 4; ++r)
                    myH[(fi * 16 + l4 * 4 + r) * HSTRIDE + fj * 16 + r15] = acc[fi][fj][r];
        if (lane < 16) {
            Zlds[wid][r15] = zs0;
            Zlds[wid][16 + r15] = zs1;
        }
    }
    __syncthreads();
    // --- combine phase 2: waves 2,3 add into regions 0,1
    if (wid >= 2) {
        float* myH = &Hlds[wid - 2][0];
#pragma unroll
        for (int fi = 0; fi < 2; ++fi)
#pragma unroll
            for (int fj = 0; fj < 8; ++fj)
#pragma unroll
                for (int r = 0; r < 4; ++r)
                    myH[(fi * 16 + l4 * 4 + r) * HSTRIDE + fj * 16 + r15] += acc[fi][fj][r];
        if (lane < 16) {
            Zlds[wid - 2][r15] += zs0;
            Zlds[wid - 2][16 + r15] += zs1;
        }
    }
    __syncthreads();

    // --- finalize: wave wid handles rows wid*8 .. wid*8+7
    const int c0 = 2 * lane;   // cols within the 128-col span
    f32x2 fc1 = *reinterpret_cast<const f32x2*>(fcW + col0 + c0);
    f32x2 fc2 = *reinterpret_cast<const f32x2*>(fcW + NH + col0 + c0);
#pragma unroll
    for (int rr = 0; rr < 8; ++rr) {
        int row = wid * 8 + rr;
        float Z = Zlds[0][row] + Zlds[1][row];
        float inv = 1.f / Z;
        f32x2 h0 = *reinterpret_cast<const f32x2*>(&Hlds[0][row * HSTRIDE + c0]);
        f32x2 h1 = *reinterpret_cast<const f32x2*>(&Hlds[1][row * HSTRIDE + c0]);
        float ha = (h0[0] + h1[0]) * inv;
        float hb = (h0[1] + h1[1]) * inv;
        ha = ha > 0.f ? ha : expm1f(ha);   // elu
        hb = hb > 0.f ? hb : expm1f(hb);
        float d1 = ha * fc1[0] + hb * fc1[1];
        float d2 = ha * fc2[0] + hb * fc2[1];
        d1 = wave_red_add(d1);
        d2 = wave_red_add(d2);
        if (lane == 0) {
            out1h[cb * NN + row0 + row] = d1;
            ph[cb * NN + row0 + row] = d2;
        }
    }
}

// ---------------- K5: c = sum(ph) + fcb; out = out1h[0]+out1h[1] + c
__global__ __launch_bounds__(256) void k5_final(const float* __restrict__ out1h,
                                                const float* __restrict__ ph,
                                                const float* __restrict__ fcb,
                                                float* __restrict__ out) {
    __shared__ float red[256];
    int t = threadIdx.x;
    float s = 0.f;
    for (int i = t; i < 2 * NN; i += 256) s += ph[i];
    red[t] = s;
    __syncthreads();
    for (int h = 128; h; h >>= 1) {
        if (t < h) red[t] += red[t + h];
        __syncthreads();
    }
    float c = red[0] + fcb[0];
    for (int i = t; i < NN; i += 256) out[i] = out1h[i] + out1h[NN + i] + c;
}

extern "C" void kernel_launch(void* const* d_in, const int* in_sizes, int n_in,
                              void* d_out, int out_size, void* d_ws, size_t ws_size,
                              hipStream_t stream) {
    const float* x   = (const float*)d_in[0];
    const int*   adj = (const int*)d_in[1];
    const float* W   = (const float*)d_in[2];
    const float* a   = (const float*)d_in[3];
    const float* fcW = (const float*)d_in[4];
    const float* fcb = (const float*)d_in[5];
    float* out = (float*)d_out;
    char* ws = (char*)d_ws;

    // total = 14,893,056 B (well under proven 35.2 MB)
    constexpr size_t oWbT   = 0;                           // 256*512*2       = 262144
    constexpr size_t oB2    = oWbT + 262144;               // 768*256*8*2     = 3145728
    constexpr size_t oWh    = oB2 + 3145728;               // 6144*256*4      = 6291456
    constexpr size_t oF1    = oWh + 6291456;               // 24576
    constexpr size_t oF2    = oF1 + 24576;                 // 24576
    constexpr size_t oMask  = oF2 + 24576;                 // 6144*96*8       = 4718592
    constexpr size_t oOut1  = oMask + 4718592;             // 2*6144*4        = 49152
    constexpr size_t oP     = oOut1 + 49152;               // 2*6144*4        = 49152

    ushort* WbT  = (ushort*)(ws + oWbT);
    ushort* B2   = (ushort*)(ws + oB2);
    float*  Wh   = (float*)(ws + oWh);
    float*  f1   = (float*)(ws + oF1);
    float*  f2   = (float*)(ws + oF2);
    unsigned long long* mk = (unsigned long long*)(ws + oMask);
    float*  out1h = (float*)(ws + oOut1);
    float*  p    = (float*)(ws + oP);

    k0_prep<<<dim3(512), dim3(256), 0, stream>>>(W, WbT);
    k1m<<<dim3(192 + NN / 4), dim3(256), 0, stream>>>(x, WbT, adj, Wh, B2, mk);
    k2_f12<<<dim3(1536), dim3(256), 0, stream>>>(Wh, a, f1, f2);
    k3_attn<<<dim3(192, 2), dim3(256), 0, stream>>>(mk, B2, f1, f2, fcW, out1h, p);
    k5_final<<<dim3(1), dim3(256), 0, stream>>>(out1h, p, fcb, out);
}

// Round 9
// 142.524 us; speedup vs baseline: 4.5497x; 1.1170x over previous
//
#include <hip/hip_runtime.h>
#include <hip/hip_bf16.h>

#define NN 6144
#define NF 512
#define NH 256
#define BR 32                  // K3 rows per block
#define NTT (NN / 64)          // 96 j-tiles total
#define NW (NN / 64)           // 96 mask words per row (24 groups x 4)
#define NG 24                  // mask groups (256 cols each)
#define HSTRIDE 132            // padded LDS row stride (f32)

typedef __attribute__((ext_vector_type(4))) float f32x4;
typedef __attribute__((ext_vector_type(2))) float f32x2;
typedef __attribute__((ext_vector_type(8))) short s16x8;
typedef __attribute__((ext_vector_type(4))) short s16x4;
typedef __attribute__((ext_vector_type(2))) unsigned long long u64x2;

__device__ __forceinline__ ushort f2bf(float f) {
    unsigned u = __builtin_bit_cast(unsigned, f);
    u += 0x7fffu + ((u >> 16) & 1u);   // RNE (finite values only)
    return (ushort)(u >> 16);
}

__device__ __forceinline__ float wave_red_add(float v) {
#pragma unroll
    for (int s = 32; s; s >>= 1) v += __shfl_xor(v, s);
    return v;
}

// ---------------- K0: W (512x256 f32, k-major) -> WbT (256x512 bf16, n-major)
__global__ __launch_bounds__(256) void k0_prep(const float* __restrict__ W,
                                               ushort* __restrict__ WbT) {
    int idx = blockIdx.x * 256 + threadIdx.x;   // 0..131071
    int k = idx >> 8, n = idx & 255;
    WbT[n * NF + k] = f2bf(W[idx]);
}

// ---------------- Kmask: adj -> interleaved u64 bitmasks. No LDS, int4 loads.
// Wave = one row. Lane l loads cols g*256 + 4l + {0..3} (int4, 1KB/wave-instr).
// ballot(v.x) = bit l -> col 4l+0: word q of group g covers cols == q (mod 4).
__global__ __launch_bounds__(256) void kmask(const int* __restrict__ adj,
                                             unsigned long long* __restrict__ maskb) {
    const int lane = threadIdx.x & 63, wid = threadIdx.x >> 6;
    const int row = blockIdx.x * 4 + wid;
    const int4* ap = reinterpret_cast<const int4*>(adj + (size_t)row * NN) + lane;
    unsigned long long* mrow = maskb + (size_t)row * NW;
#pragma unroll 4
    for (int g = 0; g < NG; ++g) {
        int4 v = ap[g * 64];   // 64 int4 = 256 ints per group
        unsigned long long w0 = __ballot(v.x != 0);
        unsigned long long w1 = __ballot(v.y != 0);
        unsigned long long w2 = __ballot(v.z != 0);
        unsigned long long w3 = __ballot(v.w != 0);
        if (lane == 0) {
            mrow[g * 4 + 0] = w0;
            mrow[g * 4 + 1] = w1;
            mrow[g * 4 + 2] = w2;
            mrow[g * 4 + 3] = w3;
        }
    }
}

// ---------------- K1: Wh = x @ W  (6144x512 * 512x256), MFMA bf16
// outputs: Wh f32 [6144][256]; B2 bf16 blocked [j/8][col][j%8]
__global__ __launch_bounds__(256) void k1_gemm(const float* __restrict__ x,
                                               const ushort* __restrict__ WbT,
                                               float* __restrict__ Wh,
                                               ushort* __restrict__ B2) {
    __shared__ ushort Asm[128 * 64];   // [row][k] swizzled
    __shared__ ushort Bsm[64 * 64];    // [n][k] swizzled
    const int t = threadIdx.x, lane = t & 63, wid = t >> 6;
    const int rb = blockIdx.x;   // 0..47 (128 rows)
    const int cb = blockIdx.y;   // 0..3  (64 cols)
    const int wrow = wid >> 1, wcol = wid & 1;
    f32x4 acc[4][2];
#pragma unroll
    for (int i = 0; i < 4; ++i)
#pragma unroll
        for (int j = 0; j < 2; ++j) acc[i][j] = (f32x4){0.f, 0.f, 0.f, 0.f};

    for (int kt = 0; kt < NF; kt += 64) {
        __syncthreads();
#pragma unroll
        for (int c = 0; c < 4; ++c) {
            int idx = c * 256 + t;           // 0..1023
            int row = idx >> 3, k8 = idx & 7;
            const float* src = x + (rb * 128 + row) * NF + kt + k8 * 8;
            float4 lo = *reinterpret_cast<const float4*>(src);
            float4 hi = *reinterpret_cast<const float4*>(src + 4);
            union { s16x8 v; ushort u[8]; } pk;
            pk.u[0] = f2bf(lo.x); pk.u[1] = f2bf(lo.y);
            pk.u[2] = f2bf(lo.z); pk.u[3] = f2bf(lo.w);
            pk.u[4] = f2bf(hi.x); pk.u[5] = f2bf(hi.y);
            pk.u[6] = f2bf(hi.z); pk.u[7] = f2bf(hi.w);
            int byte = (row * 128 + k8 * 16) ^ ((row & 7) << 4);
            *reinterpret_cast<s16x8*>((char*)Asm + byte) = pk.v;
        }
#pragma unroll
        for (int c = 0; c < 2; ++c) {
            int idx = c * 256 + t;           // 0..511
            int row = idx >> 3, k8 = idx & 7;
            s16x8 v = *reinterpret_cast<const s16x8*>(WbT + (cb * 64 + row) * NF + kt + k8 * 8);
            int byte = (row * 128 + k8 * 16) ^ ((row & 7) << 4);
            *reinterpret_cast<s16x8*>((char*)Bsm + byte) = v;
        }
        __syncthreads();
#pragma unroll
        for (int kk = 0; kk < 64; kk += 32) {
            const int kbyte = (kk + ((lane >> 4) * 8)) * 2;
            s16x8 af[4], bfr[2];
#pragma unroll
            for (int fi = 0; fi < 4; ++fi) {
                int row = wrow * 64 + fi * 16 + (lane & 15);
                int byte = (row * 128 + kbyte) ^ ((row & 7) << 4);
                af[fi] = *reinterpret_cast<const s16x8*>((char*)Asm + byte);
            }
#pragma unroll
            for (int fj = 0; fj < 2; ++fj) {
                int nn = wcol * 32 + fj * 16 + (lane & 15);
                int byte = (nn * 128 + kbyte) ^ ((nn & 7) << 4);
                bfr[fj] = *reinterpret_cast<const s16x8*>((char*)Bsm + byte);
            }
#pragma unroll
            for (int fi = 0; fi < 4; ++fi)
#pragma unroll
                for (int fj = 0; fj < 2; ++fj)
                    acc[fi][fj] = __builtin_amdgcn_mfma_f32_16x16x32_bf16(
                        af[fi], bfr[fj], acc[fi][fj], 0, 0, 0);
        }
    }
#pragma unroll
    for (int fi = 0; fi < 4; ++fi)
#pragma unroll
        for (int fj = 0; fj < 2; ++fj) {
            int grow0 = rb * 128 + wrow * 64 + fi * 16 + (lane >> 4) * 4;  // j; %8 in {0,4}
            int gcol = cb * 64 + wcol * 32 + fj * 16 + (lane & 15);
            union { s16x4 v; ushort u[4]; } pk;
#pragma unroll
            for (int r = 0; r < 4; ++r) {
                float v = acc[fi][fj][r];
                Wh[(grow0 + r) * NH + gcol] = v;
                pk.u[r] = f2bf(v);
            }
            *reinterpret_cast<s16x4*>(B2 + (grow0 >> 3) * 2048 + gcol * 8 + (grow0 & 7)) = pk.v;
        }
}

// ---------------- K2: f1 = Wh@a1, f2 = Wh@a2 (one wave per row)
__global__ __launch_bounds__(256) void k2_f12(const float* __restrict__ Wh,
                                              const float* __restrict__ a,
                                              float* __restrict__ f1,
                                              float* __restrict__ f2) {
    int row = blockIdx.x * 4 + (threadIdx.x >> 6);
    int lane = threadIdx.x & 63;
    float4 wv = *reinterpret_cast<const float4*>(Wh + row * NH + lane * 4);
    float4 a1 = *reinterpret_cast<const float4*>(a + lane * 4);
    float4 a2 = *reinterpret_cast<const float4*>(a + NH + lane * 4);
    float d1 = wv.x * a1.x + wv.y * a1.y + wv.z * a1.z + wv.w * a1.w;
    float d2 = wv.x * a2.x + wv.y * a2.y + wv.z * a2.z + wv.w * a2.w;
    d1 = wave_red_add(d1);
    d2 = wave_red_add(d2);
    if (lane == 0) { f1[row] = d1; f2[row] = d2; }
}

// ---------------- K3: fully-fused attention — FINAL rows, no partial outputs
// Block: 32 rows x 128 cols (grid 192 x 2). 4 waves; wave wid sweeps tiles
// jt = wid + it*4 (jt&3 == wid), consuming the interleaved mask format:
// bit for col C+q = (word[q&3] >> (wid*16 + l4*2 + kk*8 + (q>>2))) & 1.
__global__ __launch_bounds__(256) void k3_attn(const unsigned long long* __restrict__ maskb,
                                               const ushort* __restrict__ B2,
                                               const float* __restrict__ f1,
                                               const float* __restrict__ f2,
                                               const float* __restrict__ fcW,
                                               float* __restrict__ out1h,
                                               float* __restrict__ ph) {
    __shared__ float Hlds[2][BR * HSTRIDE];   // 2 x 16.9 KB
    __shared__ float Zlds[2][BR];
    const int t = threadIdx.x, lane = t & 63, wid = t >> 6;
    const int rb = blockIdx.x;        // 0..191 (32 rows each)
    const int cb = blockIdx.y;        // 0..1   (128 cols each)
    const int row0 = rb * BR;
    const int col0 = cb * 128;
    const int r15 = lane & 15, l4 = lane >> 4;
    const int sh = l4 * 8;
    const int base = wid * 16 + l4 * 2;   // bit base within mask words

    const float f1v0 = f1[row0 + r15];
    const float f1v1 = f1[row0 + 16 + r15];
    const unsigned long long* mp0 = maskb + (size_t)(row0 + r15) * NW;
    const unsigned long long* mp1 = mp0 + 16 * NW;
    const float* f2p = f2 + sh;
    const ushort* bb = B2 + (size_t)l4 * 2048 + (col0 + r15) * 8;

    f32x4 acc[2][8];
#pragma unroll
    for (int i = 0; i < 2; ++i)
#pragma unroll
        for (int j = 0; j < 8; ++j) acc[i][j] = (f32x4){0.f, 0.f, 0.f, 0.f};
    float zs0 = 0.f, zs1 = 0.f;

#pragma unroll 2
    for (int it = 0; it < NG; ++it) {
        const int jt = wid + it * 4;
        // group mask words (interleaved format), both row-halves
        u64x2 wAa = *reinterpret_cast<const u64x2*>(mp0 + it * 4);
        u64x2 wAb = *reinterpret_cast<const u64x2*>(mp0 + it * 4 + 2);
        u64x2 wBa = *reinterpret_cast<const u64x2*>(mp1 + it * 4);
        u64x2 wBb = *reinterpret_cast<const u64x2*>(mp1 + it * 4 + 2);
        unsigned long long wv[2][4] = {{wAa[0], wAa[1], wAb[0], wAb[1]},
                                       {wBa[0], wBa[1], wBb[0], wBb[1]}};
        f32x4 g[2][2];
#pragma unroll
        for (int kk = 0; kk < 2; ++kk)
#pragma unroll
            for (int h = 0; h < 2; ++h)
                g[kk][h] = *reinterpret_cast<const f32x4*>(f2p + jt * 64 + kk * 32 + h * 4);
        // --- wgen: build A-fragments in registers from interleaved mask bits
        s16x8 af[2][2];
#pragma unroll
        for (int fi = 0; fi < 2; ++fi) {
            const float f1v = fi ? f1v1 : f1v0;
#pragma unroll
            for (int kk = 0; kk < 2; ++kk) {
                union { s16x8 v; ushort u[8]; } pk;
                float zl = 0.f;
#pragma unroll
                for (int q = 0; q < 8; ++q) {
                    float e = f1v + g[kk][q >> 2][q & 3];
                    e = e > 0.f ? e : 0.2f * e;
                    unsigned bit = (unsigned)(wv[fi][q & 3] >> (base + kk * 8 + (q >> 2))) & 1u;
                    float w = bit ? __expf(e) : 0.f;
                    zl += w;
                    pk.u[q] = f2bf(w);
                }
                if (fi) zs1 += zl; else zs0 += zl;
                af[fi][kk] = pk.v;
            }
        }
        // --- B loads + MFMA (B2 L2-resident; 4x256B dense per instr)
#pragma unroll
        for (int kk = 0; kk < 2; ++kk) {
            const ushort* bt = bb + (size_t)(jt * 8 + kk * 4) * 2048;
#pragma unroll
            for (int fj = 0; fj < 8; ++fj) {
                s16x8 bv = *reinterpret_cast<const s16x8*>(bt + fj * 128);
                acc[0][fj] = __builtin_amdgcn_mfma_f32_16x16x32_bf16(
                    af[0][kk], bv, acc[0][fj], 0, 0, 0);
                acc[1][fj] = __builtin_amdgcn_mfma_f32_16x16x32_bf16(
                    af[1][kk], bv, acc[1][fj], 0, 0, 0);
            }
        }
    }

    // --- combine phase 1: waves 0,1 write partials
    zs0 += __shfl_xor(zs0, 16); zs0 += __shfl_xor(zs0, 32);
    zs1 += __shfl_xor(zs1, 16); zs1 += __shfl_xor(zs1, 32);
    if (wid < 2) {
        float* myH = &Hlds[wid][0];
#pragma unroll
        for (int fi = 0; fi < 2; ++fi)
#pragma unroll
            for (int fj = 0; fj < 8; ++fj)
#pragma unroll
                for (int r = 0; r < 4; ++r)
                    myH[(fi * 16 + l4 * 4 + r) * HSTRIDE + fj * 16 + r15] = acc[fi][fj][r];
        if (lane < 16) {
            Zlds[wid][r15] = zs0;
            Zlds[wid][16 + r15] = zs1;
        }
    }
    __syncthreads();
    // --- combine phase 2: waves 2,3 add into regions 0,1
    if (wid >= 2) {
        float* myH = &Hlds[wid - 2][0];
#pragma unroll
        for (int fi = 0; fi < 2; ++fi)
#pragma unroll
            for (int fj = 0; fj < 8; ++fj)
#pragma unroll
                for (int r = 0; r < 4; ++r)
                    myH[(fi * 16 + l4 * 4 + r) * HSTRIDE + fj * 16 + r15] += acc[fi][fj][r];
        if (lane < 16) {
            Zlds[wid - 2][r15] += zs0;
            Zlds[wid - 2][16 + r15] += zs1;
        }
    }
    __syncthreads();

    // --- finalize: wave wid handles rows wid*8 .. wid*8+7
    const int c0 = 2 * lane;
    f32x2 fc1 = *reinterpret_cast<const f32x2*>(fcW + col0 + c0);
    f32x2 fc2 = *reinterpret_cast<const f32x2*>(fcW + NH + col0 + c0);
#pragma unroll
    for (int rr = 0; rr < 8; ++rr) {
        int row = wid * 8 + rr;
        float Z = Zlds[0][row] + Zlds[1][row];
        float inv = 1.f / Z;
        f32x2 h0 = *reinterpret_cast<const f32x2*>(&Hlds[0][row * HSTRIDE + c0]);
        f32x2 h1 = *reinterpret_cast<const f32x2*>(&Hlds[1][row * HSTRIDE + c0]);
        float ha = (h0[0] + h1[0]) * inv;
        float hb = (h0[1] + h1[1]) * inv;
        ha = ha > 0.f ? ha : expm1f(ha);   // elu
        hb = hb > 0.f ? hb : expm1f(hb);
        float d1 = ha * fc1[0] + hb * fc1[1];
        float d2 = ha * fc2[0] + hb * fc2[1];
        d1 = wave_red_add(d1);
        d2 = wave_red_add(d2);
        if (lane == 0) {
            out1h[cb * NN + row0 + row] = d1;
            ph[cb * NN + row0 + row] = d2;
        }
    }
}

// ---------------- K5: c = sum(ph) + fcb; out = out1h[0]+out1h[1] + c
__global__ __launch_bounds__(256) void k5_final(const float* __restrict__ out1h,
                                                const float* __restrict__ ph,
                                                const float* __restrict__ fcb,
                                                float* __restrict__ out) {
    __shared__ float red[256];
    int t = threadIdx.x;
    float s = 0.f;
    for (int i = t; i < 2 * NN; i += 256) s += ph[i];
    red[t] = s;
    __syncthreads();
    for (int h = 128; h; h >>= 1) {
        if (t < h) red[t] += red[t + h];
        __syncthreads();
    }
    float c = red[0] + fcb[0];
    for (int i = t; i < NN; i += 256) out[i] = out1h[i] + out1h[NN + i] + c;
}

extern "C" void kernel_launch(void* const* d_in, const int* in_sizes, int n_in,
                              void* d_out, int out_size, void* d_ws, size_t ws_size,
                              hipStream_t stream) {
    const float* x   = (const float*)d_in[0];
    const int*   adj = (const int*)d_in[1];
    const float* W   = (const float*)d_in[2];
    const float* a   = (const float*)d_in[3];
    const float* fcW = (const float*)d_in[4];
    const float* fcb = (const float*)d_in[5];
    float* out = (float*)d_out;
    char* ws = (char*)d_ws;

    // total = 14,893,056 B (well under proven 35.2 MB)
    constexpr size_t oWbT   = 0;                           // 256*512*2       = 262144
    constexpr size_t oB2    = oWbT + 262144;               // 768*256*8*2     = 3145728
    constexpr size_t oWh    = oB2 + 3145728;               // 6144*256*4      = 6291456
    constexpr size_t oF1    = oWh + 6291456;               // 24576
    constexpr size_t oF2    = oF1 + 24576;                 // 24576
    constexpr size_t oMask  = oF2 + 24576;                 // 6144*96*8       = 4718592
    constexpr size_t oOut1  = oMask + 4718592;             // 2*6144*4        = 49152
    constexpr size_t oP     = oOut1 + 49152;               // 2*6144*4        = 49152

    ushort* WbT  = (ushort*)(ws + oWbT);
    ushort* B2   = (ushort*)(ws + oB2);
    float*  Wh   = (float*)(ws + oWh);
    float*  f1   = (float*)(ws + oF1);
    float*  f2   = (float*)(ws + oF2);
    unsigned long long* mk = (unsigned long long*)(ws + oMask);
    float*  out1h = (float*)(ws + oOut1);
    float*  p    = (float*)(ws + oP);

    k0_prep<<<dim3(512), dim3(256), 0, stream>>>(W, WbT);
    kmask<<<dim3(NN / 4), dim3(256), 0, stream>>>(adj, mk);
    k1_gemm<<<dim3(48, 4), dim3(256), 0, stream>>>(x, WbT, Wh, B2);
    k2_f12<<<dim3(1536), dim3(256), 0, stream>>>(Wh, a, f1, f2);
    k3_attn<<<dim3(192, 2), dim3(256), 0, stream>>>(mk, B2, f1, f2, fcW, out1h, p);
    k5_final<<<dim3(1), dim3(256), 0, stream>>>(out1h, p, fcb, out);
}